// Round 1
// baseline (693.092 us; speedup 1.0000x reference)
//
#include <hip/hip_runtime.h>
#include <math.h>

#define NTOK   16384
#define HDIM   1024
#define HHALF  512
#define NE     16

#define TPB    64      // tokens per block (kernel 1)
#define KC     16      // K rows staged per chunk
#define NTHR   512

// d_out layout (concatenated reference outputs, all f32; indices stored as float)
#define OFF_TP  0
#define OFF_TI  (NTOK * 2)
#define OFF_DEC (NTOK * 4)
#define OFF_PH  (OFF_DEC + NTOK * NE)
#define OFF_PR  (OFF_PH + NTOK * NE)

__device__ __forceinline__ float gelu_exact(float x) {
    return 0.5f * x * (1.0f + erff(x * 0.70710678118654752440f));
}

// Kernel 1: both MLPs. Writes tanh(raw_p)*pi to OFF_PH, raw_amps (pre-softmax) to OFF_PR.
__global__ void __launch_bounds__(NTHR)
qir_mlp(const float* __restrict__ xg,
        const float* __restrict__ w1a, const float* __restrict__ b1a,
        const float* __restrict__ w2a, const float* __restrict__ b2a,
        const float* __restrict__ w1p, const float* __restrict__ b1p,
        const float* __restrict__ w2p, const float* __restrict__ b2p,
        float* __restrict__ out)
{
    __shared__ float sh_w[KC][HHALF];   // 32 KB
    __shared__ float sh_x[KC][68];      // 4.25 KB, transposed [k][token], padded stride

    const int tid  = threadIdx.x;
    const int cg   = tid & 63;          // lane within wave = column group
    const int tg   = tid >> 6;          // wave id 0..7 = token group
    const int tok0 = blockIdx.x * TPB;
    const int cA   = cg * 4;            // cols cA..cA+3 and cB..cB+3 per thread
    const int cB   = 256 + cg * 4;

    for (int phase = 0; phase < 2; ++phase) {
        const float* __restrict__ w1 = phase ? w1p : w1a;
        const float* __restrict__ b1 = phase ? b1p : b1a;
        const float* __restrict__ w2 = phase ? w2p : w2a;
        const float* __restrict__ b2 = phase ? b2p : b2a;

        float acc[8][8];
        #pragma unroll
        for (int t = 0; t < 8; ++t)
            #pragma unroll
            for (int c = 0; c < 8; ++c) acc[t][c] = 0.0f;

        float4 wreg[4];
        float4 xreg = make_float4(0.f, 0.f, 0.f, 0.f);

        auto load_chunk = [&](int kc) {
            #pragma unroll
            for (int p = 0; p < 4; ++p) {
                int f  = tid + p * NTHR;            // float4 index 0..2047
                int k  = f >> 7;
                int c4 = (f & 127) << 2;
                wreg[p] = *(const float4*)&w1[(kc * KC + k) * HHALF + c4];
            }
            if (tid < 256) {
                int t  = tid >> 2;                  // token 0..63
                int k4 = (tid & 3) << 2;            // k offset 0,4,8,12
                xreg = *(const float4*)&xg[(tok0 + t) * HDIM + kc * KC + k4];
            }
        };

        load_chunk(0);
        for (int kc = 0; kc < HDIM / KC; ++kc) {
            __syncthreads();   // prior chunk's LDS reads complete before overwrite
            #pragma unroll
            for (int p = 0; p < 4; ++p) {
                int f  = tid + p * NTHR;
                int k  = f >> 7;
                int c4 = (f & 127) << 2;
                *(float4*)&sh_w[k][c4] = wreg[p];
            }
            if (tid < 256) {
                int t  = tid >> 2;
                int k4 = (tid & 3) << 2;
                sh_x[k4 + 0][t] = xreg.x;
                sh_x[k4 + 1][t] = xreg.y;
                sh_x[k4 + 2][t] = xreg.z;
                sh_x[k4 + 3][t] = xreg.w;
            }
            __syncthreads();
            if (kc + 1 < HDIM / KC) load_chunk(kc + 1);   // prefetch under compute

            #pragma unroll 4
            for (int k = 0; k < KC; ++k) {
                float4 xa = *(const float4*)&sh_x[k][tg * 8];       // wave-broadcast
                float4 xb = *(const float4*)&sh_x[k][tg * 8 + 4];
                float4 wa = *(const float4*)&sh_w[k][cA];
                float4 wb = *(const float4*)&sh_w[k][cB];
                float xs[8] = {xa.x, xa.y, xa.z, xa.w, xb.x, xb.y, xb.z, xb.w};
                float ws[8] = {wa.x, wa.y, wa.z, wa.w, wb.x, wb.y, wb.z, wb.w};
                #pragma unroll
                for (int t = 0; t < 8; ++t)
                    #pragma unroll
                    for (int c = 0; c < 8; ++c)
                        acc[t][c] = fmaf(xs[t], ws[c], acc[t][c]);
            }
        }

        // bias + exact-erf gelu, in place
        {
            float4 bA4 = *(const float4*)&b1[cA];
            float4 bB4 = *(const float4*)&b1[cB];
            float bs[8] = {bA4.x, bA4.y, bA4.z, bA4.w, bB4.x, bB4.y, bB4.z, bB4.w};
            #pragma unroll
            for (int t = 0; t < 8; ++t)
                #pragma unroll
                for (int c = 0; c < 8; ++c)
                    acc[t][c] = gelu_exact(acc[t][c] + bs[c]);
        }

        // fused 512->16 projection: wave tg owns tokens tok0+tg*8..+7, its 64 lanes
        // cover all 512 columns -> butterfly-reduce across the wave.
        for (int e = 0; e < NE; ++e) {
            float w2v[8];
            #pragma unroll
            for (int j = 0; j < 4; ++j) {
                w2v[j]     = w2[(cA + j) * NE + e];
                w2v[4 + j] = w2[(cB + j) * NE + e];
            }
            float bias2 = b2[e];
            #pragma unroll
            for (int t = 0; t < 8; ++t) {
                float s = 0.0f;
                #pragma unroll
                for (int j = 0; j < 8; ++j) s = fmaf(acc[t][j], w2v[j], s);
                #pragma unroll
                for (int off = 1; off < 64; off <<= 1)
                    s += __shfl_xor(s, off, 64);
                if (cg == 0) {
                    float raw   = s + bias2;
                    int   token = tok0 + tg * 8 + t;
                    if (phase)
                        out[OFF_PH + token * NE + e] = tanhf(raw) * 3.14159265358979323846f;
                    else
                        out[OFF_PR + token * NE + e] = raw;   // scratch: raw amps
                }
            }
        }
    }
}

// Kernel 2: per-token epilogue. Reads raw amps from OFF_PR, overwrites with final probs.
__global__ void __launch_bounds__(256)
qir_epilogue(const float* __restrict__ ent, float* __restrict__ out)
{
    __shared__ float sh_c[120], sh_s[120];
    const int tid = threadIdx.x;
    if (tid < 120) {
        int rem = tid, i = 0;
        while (rem >= 15 - i) { rem -= 15 - i; ++i; }   // row i has 15-i pairs
        int j = i + 1 + rem;
        float ang = ent[i * NE + j] * 0.5f;             // ENT_STRENGTH = 0.5
        sh_c[tid] = cosf(ang);
        sh_s[tid] = sinf(ang);
    }
    __syncthreads();

    const int token = blockIdx.x * 256 + tid;

    float a[16];
    #pragma unroll
    for (int q = 0; q < 4; ++q) {
        float4 v = *(const float4*)&out[OFF_PR + token * NE + q * 4];
        a[q*4+0] = v.x; a[q*4+1] = v.y; a[q*4+2] = v.z; a[q*4+3] = v.w;
    }

    // amplitudes = sqrt(softmax(|raw|))
    float m = fabsf(a[0]);
    #pragma unroll
    for (int e = 1; e < 16; ++e) m = fmaxf(m, fabsf(a[e]));
    float ssum = 0.0f;
    #pragma unroll
    for (int e = 0; e < 16; ++e) { a[e] = expf(fabsf(a[e]) - m); ssum += a[e]; }
    float inv = 1.0f / ssum;
    #pragma unroll
    for (int e = 0; e < 16; ++e) a[e] = sqrtf(a[e] * inv);

    // 120 sequential Givens rotations, fully unrolled (constant indices)
    {
        int p = 0;
        #pragma unroll
        for (int i = 0; i < 16; ++i) {
            #pragma unroll
            for (int j = i + 1; j < 16; ++j) {
                float c = sh_c[p], s = sh_s[p]; ++p;
                float ai = a[i], aj = a[j];
                a[i] = c * ai - s * aj;
                a[j] = s * ai + c * aj;
            }
        }
    }

    // decoherent = entangled (coherence factor = exp(0) = 1)
    #pragma unroll
    for (int q = 0; q < 4; ++q)
        *(float4*)&out[OFF_DEC + token * NE + q * 4] =
            make_float4(a[q*4], a[q*4+1], a[q*4+2], a[q*4+3]);

    // probs = dec^2, L1-normalized
    float pr[16];
    float s2 = 0.0f;
    #pragma unroll
    for (int e = 0; e < 16; ++e) { pr[e] = a[e] * a[e]; s2 += pr[e]; }
    float inv2 = 1.0f / fmaxf(s2, 1e-12f);
    #pragma unroll
    for (int e = 0; e < 16; ++e) pr[e] *= inv2;
    #pragma unroll
    for (int q = 0; q < 4; ++q)
        *(float4*)&out[OFF_PR + token * NE + q * 4] =
            make_float4(pr[q*4], pr[q*4+1], pr[q*4+2], pr[q*4+3]);

    // top-2 (strict > == lowest index on ties, matching lax.top_k)
    float bv = pr[0]; int bi = 0;
    #pragma unroll
    for (int e = 1; e < 16; ++e) if (pr[e] > bv) { bv = pr[e]; bi = e; }
    float sv = -1.0f; int si = 0;
    #pragma unroll
    for (int e = 0; e < 16; ++e) if (e != bi && pr[e] > sv) { sv = pr[e]; si = e; }
    float ts = fmaxf(fabsf(bv) + fabsf(sv), 1e-12f);
    out[OFF_TP + token * 2 + 0] = bv / ts;
    out[OFF_TP + token * 2 + 1] = sv / ts;
    out[OFF_TI + token * 2 + 0] = (float)bi;
    out[OFF_TI + token * 2 + 1] = (float)si;
}

extern "C" void kernel_launch(void* const* d_in, const int* in_sizes, int n_in,
                              void* d_out, int out_size, void* d_ws, size_t ws_size,
                              hipStream_t stream) {
    const float* xg  = (const float*)d_in[0];
    const float* w1a = (const float*)d_in[1];
    const float* b1a = (const float*)d_in[2];
    const float* w2a = (const float*)d_in[3];
    const float* b2a = (const float*)d_in[4];
    const float* w1p = (const float*)d_in[5];
    const float* b1p = (const float*)d_in[6];
    const float* w2p = (const float*)d_in[7];
    const float* b2p = (const float*)d_in[8];
    const float* ent = (const float*)d_in[9];
    float* out = (float*)d_out;

    qir_mlp<<<NTOK / TPB, NTHR, 0, stream>>>(xg, w1a, b1a, w2a, b2a,
                                             w1p, b1p, w2p, b2p, out);
    qir_epilogue<<<NTOK / 256, 256, 0, stream>>>(ent, out);
}

// Round 2
// 156.698 us; speedup vs baseline: 4.4231x; 4.4231x over previous
//
#include <hip/hip_runtime.h>
#include <math.h>

#define NTOK   16384
#define HDIM   1024
#define HHALF  512
#define NE     16

// d_out layout (concatenated reference outputs, all f32; indices stored as float)
#define OFF_TP  0
#define OFF_TI  (NTOK * 2)
#define OFF_DEC (NTOK * 4)
#define OFF_PH  (OFF_DEC + NTOK * NE)
#define OFF_PR  (OFF_PH + NTOK * NE)

typedef _Float16 half8 __attribute__((ext_vector_type(8)));
typedef _Float16 half4 __attribute__((ext_vector_type(4)));
typedef float f32x16 __attribute__((ext_vector_type(16)));
typedef float f32x4 __attribute__((ext_vector_type(4)));

typedef __attribute__((address_space(3))) void lds_void_t;
typedef const __attribute__((address_space(1))) void gbl_void_t;

#define LO_SCALE     2048.0f
#define LO_SCALE_INV (1.0f / 2048.0f)

__device__ __forceinline__ float gelu_exact(float x) {
    return 0.5f * x * (1.0f + erff(x * 0.70710678118654752440f));
}

// ---------------------------------------------------------------------------
// Prologue: W[1024][512] f32 (both phases) -> d_ws as f16 hi/lo planes, laid
// out as the EXACT swizzled 64KB-per-BK32 LDS image so the GEMM can stage B
// with linear global_load_lds.
// Image per (phase, kc): 512 rows n x 128 B; row = [hi k0..31 | lo k0..31] f16,
// 16B-granule g' = g ^ (n&7). lo is pre-scaled by 2048 (f16-subnormal fix).
// ---------------------------------------------------------------------------
__global__ void __launch_bounds__(256)
qir_wtrans(const float* __restrict__ w1a, const float* __restrict__ w1p,
           _Float16* __restrict__ wt)
{
    int u  = blockIdx.x * 256 + threadIdx.x;   // 0..262143
    int p  = u >> 17;
    int r  = u & 131071;
    int kc = r >> 12;
    int q  = r & 4095;
    int n  = q >> 3;
    int gp = q & 7;
    int g  = gp ^ (n & 7);
    int k0 = kc * 32 + (g & 3) * 8;
    const float* __restrict__ W = p ? w1p : w1a;
    half8 v;
    #pragma unroll
    for (int j = 0; j < 8; ++j) {
        float x = W[(size_t)(k0 + j) * HHALF + n];
        _Float16 h = (_Float16)x;
        v[j] = (g >> 2) ? (_Float16)((x - (float)h) * LO_SCALE) : h;
    }
    *(half8*)&wt[((size_t)(p * 32 + kc) << 15) + (n << 6) + (gp << 3)] = v;
}

// ---------------------------------------------------------------------------
// Main GEMM: per block = 64 tokens x all 512 cols x one phase.
// f16x3 split MFMA (32x32x16), double-buffered LDS, fused bias+gelu+GEMM2.
// ---------------------------------------------------------------------------
__global__ void __launch_bounds__(512, 2)
qir_gemm(const float* __restrict__ xg, const _Float16* __restrict__ wt,
         const float* __restrict__ b1a, const float* __restrict__ w2a, const float* __restrict__ b2a,
         const float* __restrict__ b1p, const float* __restrict__ w2p, const float* __restrict__ b2p,
         float* __restrict__ out)
{
    extern __shared__ char smem[];
    const int tid = threadIdx.x;
    const int l   = tid & 63;
    const int w   = tid >> 6;
    const int mblk  = blockIdx.x >> 1;
    const int phase = blockIdx.x & 1;
    const int tok0  = mblk * 64;

    const float* __restrict__ b1 = phase ? b1p : b1a;
    const float* __restrict__ w2 = phase ? w2p : w2a;
    const float* __restrict__ b2 = phase ? b2p : b2a;
    const _Float16* __restrict__ wtp = wt + ((size_t)phase << 20);  // 32*32768 f16/phase

    // LDS map: buf0 = [A0 8K | B0 64K] at 0, buf1 at 73728. Epilogue reuses:
    // H (per-wave 8K, 64K total) in buf0; partials P (32K) at 73728.
    char* const A0 = smem;
    char* const B0 = smem + 8192;
    char* const A1 = smem + 73728;
    char* const B1 = smem + 73728 + 8192;

    // A staging: thread -> (row ar, k-quad akq)
    const int ar  = tid >> 3;
    const int akq = tid & 7;
    const float* __restrict__ aptr = xg + (size_t)(tok0 + ar) * HDIM + akq * 4;
    const int aswz    = (ar & 7) << 4;
    const int ahi_off = ar * 128 + ((akq * 8) ^ aswz);
    const int alo_off = ar * 128 + ((64 + akq * 8) ^ aswz);

    f32x16 acc[2][2];   // hi*hi + lo*hi
    f32x16 accs[2][2];  // hi*(lo*2048), combined later * 1/2048
    #pragma unroll
    for (int mf = 0; mf < 2; ++mf)
        #pragma unroll
        for (int nf = 0; nf < 2; ++nf)
            #pragma unroll
            for (int rg = 0; rg < 16; ++rg) { acc[mf][nf][rg] = 0.0f; accs[mf][nf][rg] = 0.0f; }

    const int lrow = l & 31;
    const int lswz = (l & 7) << 4;
    const int lkoff = (l >> 5) << 4;   // byte offset of this lane's k-octet

    // ---- prologue stage kc=0 ----
    float4 areg = *(const float4*)aptr;
    {
        const _Float16* gp0 = wtp + (w * 8) * 512 + l * 8;
        char* lp0 = B0 + (w * 8) * 1024;
        #pragma unroll
        for (int q = 0; q < 8; ++q)
            __builtin_amdgcn_global_load_lds((gbl_void_t*)(gp0 + q * 512),
                                             (lds_void_t*)(lp0 + q * 1024), 16, 0, 0);
    }
    {
        _Float16 h0 = (_Float16)areg.x, h1 = (_Float16)areg.y,
                 h2 = (_Float16)areg.z, h3 = (_Float16)areg.w;
        half4 hv = {h0, h1, h2, h3};
        half4 lv = {(_Float16)(areg.x - (float)h0), (_Float16)(areg.y - (float)h1),
                    (_Float16)(areg.z - (float)h2), (_Float16)(areg.w - (float)h3)};
        *(half4*)(A0 + ahi_off) = hv;
        *(half4*)(A0 + alo_off) = lv;
    }
    __syncthreads();

    // ---- main K loop ----
    #pragma unroll 1
    for (int kc = 0; kc < 32; ++kc) {
        const int s = kc & 1;
        char* const A  = s ? A1 : A0;
        char* const B  = s ? B1 : B0;
        char* const An = s ? A0 : A1;
        char* const Bn = s ? B0 : B1;

        if (kc + 1 < 32) {
            areg = *(const float4*)(aptr + (kc + 1) * 32);
            const _Float16* gpn = wtp + (size_t)(kc + 1) * 32768 + (w * 8) * 512 + l * 8;
            char* lpn = Bn + (w * 8) * 1024;
            #pragma unroll
            for (int q = 0; q < 8; ++q)
                __builtin_amdgcn_global_load_lds((gbl_void_t*)(gpn + q * 512),
                                                 (lds_void_t*)(lpn + q * 1024), 16, 0, 0);
        }

        #pragma unroll
        for (int kh = 0; kh < 2; ++kh) {
            const int koff = kh * 32 + lkoff;
            const char* Ar0 = A + lrow * 128;
            const char* Ar1 = A + (32 + lrow) * 128;
            const char* Br0 = B + (w * 64 + lrow) * 128;
            const char* Br1 = B + (w * 64 + 32 + lrow) * 128;
            half8 ah0 = *(const half8*)(Ar0 + (koff ^ lswz));
            half8 al0 = *(const half8*)(Ar0 + ((64 + koff) ^ lswz));
            half8 ah1 = *(const half8*)(Ar1 + (koff ^ lswz));
            half8 al1 = *(const half8*)(Ar1 + ((64 + koff) ^ lswz));
            half8 bh0 = *(const half8*)(Br0 + (koff ^ lswz));
            half8 bl0 = *(const half8*)(Br0 + ((64 + koff) ^ lswz));
            half8 bh1 = *(const half8*)(Br1 + (koff ^ lswz));
            half8 bl1 = *(const half8*)(Br1 + ((64 + koff) ^ lswz));

            acc[0][0]  = __builtin_amdgcn_mfma_f32_32x32x16_f16(ah0, bh0, acc[0][0], 0, 0, 0);
            acc[0][0]  = __builtin_amdgcn_mfma_f32_32x32x16_f16(al0, bh0, acc[0][0], 0, 0, 0);
            accs[0][0] = __builtin_amdgcn_mfma_f32_32x32x16_f16(ah0, bl0, accs[0][0], 0, 0, 0);
            acc[0][1]  = __builtin_amdgcn_mfma_f32_32x32x16_f16(ah0, bh1, acc[0][1], 0, 0, 0);
            acc[0][1]  = __builtin_amdgcn_mfma_f32_32x32x16_f16(al0, bh1, acc[0][1], 0, 0, 0);
            accs[0][1] = __builtin_amdgcn_mfma_f32_32x32x16_f16(ah0, bl1, accs[0][1], 0, 0, 0);
            acc[1][0]  = __builtin_amdgcn_mfma_f32_32x32x16_f16(ah1, bh0, acc[1][0], 0, 0, 0);
            acc[1][0]  = __builtin_amdgcn_mfma_f32_32x32x16_f16(al1, bh0, acc[1][0], 0, 0, 0);
            accs[1][0] = __builtin_amdgcn_mfma_f32_32x32x16_f16(ah1, bl0, accs[1][0], 0, 0, 0);
            acc[1][1]  = __builtin_amdgcn_mfma_f32_32x32x16_f16(ah1, bh1, acc[1][1], 0, 0, 0);
            acc[1][1]  = __builtin_amdgcn_mfma_f32_32x32x16_f16(al1, bh1, acc[1][1], 0, 0, 0);
            accs[1][1] = __builtin_amdgcn_mfma_f32_32x32x16_f16(ah1, bl1, accs[1][1], 0, 0, 0);
        }

        if (kc + 1 < 32) {
            _Float16 h0 = (_Float16)areg.x, h1 = (_Float16)areg.y,
                     h2 = (_Float16)areg.z, h3 = (_Float16)areg.w;
            half4 hv = {h0, h1, h2, h3};
            half4 lv = {(_Float16)(areg.x - (float)h0), (_Float16)(areg.y - (float)h1),
                        (_Float16)(areg.z - (float)h2), (_Float16)(areg.w - (float)h3)};
            *(half4*)(An + ahi_off) = hv;
            *(half4*)(An + alo_off) = lv;
        }
        __syncthreads();
    }

    // ---- combine split accumulators, bias + exact gelu ----
    const float bb0 = b1[w * 64 + lrow];
    const float bb1 = b1[w * 64 + 32 + lrow];
    #pragma unroll
    for (int mf = 0; mf < 2; ++mf)
        #pragma unroll
        for (int nf = 0; nf < 2; ++nf) {
            const float bb = nf ? bb1 : bb0;
            #pragma unroll
            for (int rg = 0; rg < 16; ++rg) {
                float v = acc[mf][nf][rg] + accs[mf][nf][rg] * LO_SCALE_INV + bb;
                acc[mf][nf][rg] = gelu_exact(v);
            }
        }

    // ---- fused GEMM2: raw[64][16] = h[64][512] @ w2, f16x3 via per-wave K-slice ----
    char* const H = smem + w * 8192;   // wave-private h slice [64 rows][64 f16] swizzled

    // pass 1: stage h_hi, products a_hi*w2_hi + a_hi*w2_lo'
    #pragma unroll
    for (int mf = 0; mf < 2; ++mf)
        #pragma unroll
        for (int nf = 0; nf < 2; ++nf)
            #pragma unroll
            for (int rg = 0; rg < 16; ++rg) {
                int row = mf * 32 + (rg & 3) + 8 * (rg >> 2) + 4 * (l >> 5);
                int c   = nf * 32 + lrow;
                *(_Float16*)(H + row * 128 + ((2 * c) ^ ((row & 7) << 4))) =
                    (_Float16)acc[mf][nf][rg];
            }

    f32x4 acc2[4], acc2s[4];
    #pragma unroll
    for (int mf = 0; mf < 4; ++mf)
        #pragma unroll
        for (int rg = 0; rg < 4; ++rg) { acc2[mf][rg] = 0.0f; acc2s[mf][rg] = 0.0f; }

    half8 w2h[2], w2l[2];
    #pragma unroll
    for (int ks = 0; ks < 2; ++ks) {
        #pragma unroll
        for (int j = 0; j < 8; ++j) {
            int kg = w * 64 + ks * 32 + ((l >> 4) << 3) + j;
            float v = w2[(size_t)kg * NE + (l & 15)];
            _Float16 h = (_Float16)v;
            w2h[ks][j] = h;
            w2l[ks][j] = (_Float16)((v - (float)h) * LO_SCALE);
        }
        const int k2off = ks * 64 + ((l >> 4) << 4);
        #pragma unroll
        for (int mf = 0; mf < 4; ++mf) {
            int row = mf * 16 + (l & 15);
            half8 a2 = *(const half8*)(H + row * 128 + (k2off ^ ((row & 7) << 4)));
            acc2[mf]  = __builtin_amdgcn_mfma_f32_16x16x32_f16(a2, w2h[ks], acc2[mf], 0, 0, 0);
            acc2s[mf] = __builtin_amdgcn_mfma_f32_16x16x32_f16(a2, w2l[ks], acc2s[mf], 0, 0, 0);
        }
    }

    // pass 2: stage h_lo over same region, product a_lo*w2_hi
    #pragma unroll
    for (int mf = 0; mf < 2; ++mf)
        #pragma unroll
        for (int nf = 0; nf < 2; ++nf)
            #pragma unroll
            for (int rg = 0; rg < 16; ++rg) {
                int row = mf * 32 + (rg & 3) + 8 * (rg >> 2) + 4 * (l >> 5);
                int c   = nf * 32 + lrow;
                float v = acc[mf][nf][rg];
                _Float16 h = (_Float16)v;
                *(_Float16*)(H + row * 128 + ((2 * c) ^ ((row & 7) << 4))) =
                    (_Float16)(v - (float)h);
            }
    #pragma unroll
    for (int ks = 0; ks < 2; ++ks) {
        const int k2off = ks * 64 + ((l >> 4) << 4);
        #pragma unroll
        for (int mf = 0; mf < 4; ++mf) {
            int row = mf * 16 + (l & 15);
            half8 a2 = *(const half8*)(H + row * 128 + (k2off ^ ((row & 7) << 4)));
            acc2[mf] = __builtin_amdgcn_mfma_f32_16x16x32_f16(a2, w2h[ks], acc2[mf], 0, 0, 0);
        }
    }

    // ---- cross-wave reduction of GEMM2 partials ----
    float* const P = (float*)(smem + 73728);   // [8 waves][64 tok][16 e]
    #pragma unroll
    for (int mf = 0; mf < 4; ++mf)
        #pragma unroll
        for (int rg = 0; rg < 4; ++rg) {
            int row = mf * 16 + ((l >> 4) << 2) + rg;
            P[(w * 64 + row) * NE + (l & 15)] = acc2[mf][rg] + acc2s[mf][rg] * LO_SCALE_INV;
        }
    __syncthreads();

    #pragma unroll
    for (int rep = 0; rep < 2; ++rep) {
        int oi = tid + rep * 512;
        int tk = oi >> 4, e = oi & 15;
        float sum = b2[e];
        #pragma unroll
        for (int w8 = 0; w8 < 8; ++w8) sum += P[(w8 * 64 + tk) * NE + e];
        size_t gi = (size_t)(tok0 + tk) * NE + e;
        if (phase) out[OFF_PH + gi] = tanhf(sum) * 3.14159265358979323846f;
        else       out[OFF_PR + gi] = sum;
    }
}

// ---------------------------------------------------------------------------
// Fallback (proven R1 kernel) if ws_size is too small for the WT image.
// ---------------------------------------------------------------------------
__global__ void __launch_bounds__(512)
qir_mlp(const float* __restrict__ xg,
        const float* __restrict__ w1a, const float* __restrict__ b1a,
        const float* __restrict__ w2a, const float* __restrict__ b2a,
        const float* __restrict__ w1p, const float* __restrict__ b1p,
        const float* __restrict__ w2p, const float* __restrict__ b2p,
        float* __restrict__ out)
{
    __shared__ float sh_w[16][HHALF];
    __shared__ float sh_x[16][68];

    const int tid  = threadIdx.x;
    const int cg   = tid & 63;
    const int tg   = tid >> 6;
    const int tok0 = blockIdx.x * 64;
    const int cA   = cg * 4;
    const int cB   = 256 + cg * 4;

    for (int phase = 0; phase < 2; ++phase) {
        const float* __restrict__ w1 = phase ? w1p : w1a;
        const float* __restrict__ b1 = phase ? b1p : b1a;
        const float* __restrict__ w2 = phase ? w2p : w2a;
        const float* __restrict__ b2 = phase ? b2p : b2a;

        float acc[8][8];
        #pragma unroll
        for (int t = 0; t < 8; ++t)
            #pragma unroll
            for (int c = 0; c < 8; ++c) acc[t][c] = 0.0f;

        float4 wreg[4];
        float4 xreg = make_float4(0.f, 0.f, 0.f, 0.f);

        auto load_chunk = [&](int kc) {
            #pragma unroll
            for (int p = 0; p < 4; ++p) {
                int f  = tid + p * 512;
                int k  = f >> 7;
                int c4 = (f & 127) << 2;
                wreg[p] = *(const float4*)&w1[(kc * 16 + k) * HHALF + c4];
            }
            if (tid < 256) {
                int t  = tid >> 2;
                int k4 = (tid & 3) << 2;
                xreg = *(const float4*)&xg[(size_t)(tok0 + t) * HDIM + kc * 16 + k4];
            }
        };

        load_chunk(0);
        for (int kc = 0; kc < HDIM / 16; ++kc) {
            __syncthreads();
            #pragma unroll
            for (int p = 0; p < 4; ++p) {
                int f  = tid + p * 512;
                int k  = f >> 7;
                int c4 = (f & 127) << 2;
                *(float4*)&sh_w[k][c4] = wreg[p];
            }
            if (tid < 256) {
                int t  = tid >> 2;
                int k4 = (tid & 3) << 2;
                sh_x[k4 + 0][t] = xreg.x;
                sh_x[k4 + 1][t] = xreg.y;
                sh_x[k4 + 2][t] = xreg.z;
                sh_x[k4 + 3][t] = xreg.w;
            }
            __syncthreads();
            if (kc + 1 < HDIM / 16) load_chunk(kc + 1);

            #pragma unroll 4
            for (int k = 0; k < 16; ++k) {
                float4 xa = *(const float4*)&sh_x[k][tg * 8];
                float4 xb = *(const float4*)&sh_x[k][tg * 8 + 4];
                float4 wa = *(const float4*)&sh_w[k][cA];
                float4 wb = *(const float4*)&sh_w[k][cB];
                float xs[8] = {xa.x, xa.y, xa.z, xa.w, xb.x, xb.y, xb.z, xb.w};
                float ws[8] = {wa.x, wa.y, wa.z, wa.w, wb.x, wb.y, wb.z, wb.w};
                #pragma unroll
                for (int t = 0; t < 8; ++t)
                    #pragma unroll
                    for (int c = 0; c < 8; ++c)
                        acc[t][c] = fmaf(xs[t], ws[c], acc[t][c]);
            }
        }

        {
            float4 bA4 = *(const float4*)&b1[cA];
            float4 bB4 = *(const float4*)&b1[cB];
            float bs[8] = {bA4.x, bA4.y, bA4.z, bA4.w, bB4.x, bB4.y, bB4.z, bB4.w};
            #pragma unroll
            for (int t = 0; t < 8; ++t)
                #pragma unroll
                for (int c = 0; c < 8; ++c)
                    acc[t][c] = gelu_exact(acc[t][c] + bs[c]);
        }

        for (int e = 0; e < NE; ++e) {
            float w2v[8];
            #pragma unroll
            for (int j = 0; j < 4; ++j) {
                w2v[j]     = w2[(cA + j) * NE + e];
                w2v[4 + j] = w2[(cB + j) * NE + e];
            }
            float bias2 = b2[e];
            #pragma unroll
            for (int t = 0; t < 8; ++t) {
                float s = 0.0f;
                #pragma unroll
                for (int j = 0; j < 8; ++j) s = fmaf(acc[t][j], w2v[j], s);
                #pragma unroll
                for (int off = 1; off < 64; off <<= 1)
                    s += __shfl_xor(s, off, 64);
                if (cg == 0) {
                    float raw   = s + bias2;
                    int   token = tok0 + tg * 8 + t;
                    if (phase)
                        out[OFF_PH + (size_t)token * NE + e] = tanhf(raw) * 3.14159265358979323846f;
                    else
                        out[OFF_PR + (size_t)token * NE + e] = raw;
                }
            }
        }
    }
}

// ---------------------------------------------------------------------------
// Per-token epilogue (unchanged, proven in R1)
// ---------------------------------------------------------------------------
__global__ void __launch_bounds__(256)
qir_epilogue(const float* __restrict__ ent, float* __restrict__ out)
{
    __shared__ float sh_c[120], sh_s[120];
    const int tid = threadIdx.x;
    if (tid < 120) {
        int rem = tid, i = 0;
        while (rem >= 15 - i) { rem -= 15 - i; ++i; }
        int j = i + 1 + rem;
        float ang = ent[i * NE + j] * 0.5f;
        sh_c[tid] = cosf(ang);
        sh_s[tid] = sinf(ang);
    }
    __syncthreads();

    const int token = blockIdx.x * 256 + tid;

    float a[16];
    #pragma unroll
    for (int q = 0; q < 4; ++q) {
        float4 v = *(const float4*)&out[OFF_PR + (size_t)token * NE + q * 4];
        a[q*4+0] = v.x; a[q*4+1] = v.y; a[q*4+2] = v.z; a[q*4+3] = v.w;
    }

    float m = fabsf(a[0]);
    #pragma unroll
    for (int e = 1; e < 16; ++e) m = fmaxf(m, fabsf(a[e]));
    float ssum = 0.0f;
    #pragma unroll
    for (int e = 0; e < 16; ++e) { a[e] = expf(fabsf(a[e]) - m); ssum += a[e]; }
    float inv = 1.0f / ssum;
    #pragma unroll
    for (int e = 0; e < 16; ++e) a[e] = sqrtf(a[e] * inv);

    {
        int p = 0;
        #pragma unroll
        for (int i = 0; i < 16; ++i) {
            #pragma unroll
            for (int j = i + 1; j < 16; ++j) {
                float c = sh_c[p], s = sh_s[p]; ++p;
                float ai = a[i], aj = a[j];
                a[i] = c * ai - s * aj;
                a[j] = s * ai + c * aj;
            }
        }
    }

    #pragma unroll
    for (int q = 0; q < 4; ++q)
        *(float4*)&out[OFF_DEC + (size_t)token * NE + q * 4] =
            make_float4(a[q*4], a[q*4+1], a[q*4+2], a[q*4+3]);

    float pr[16];
    float s2 = 0.0f;
    #pragma unroll
    for (int e = 0; e < 16; ++e) { pr[e] = a[e] * a[e]; s2 += pr[e]; }
    float inv2 = 1.0f / fmaxf(s2, 1e-12f);
    #pragma unroll
    for (int e = 0; e < 16; ++e) pr[e] *= inv2;
    #pragma unroll
    for (int q = 0; q < 4; ++q)
        *(float4*)&out[OFF_PR + (size_t)token * NE + q * 4] =
            make_float4(pr[q*4], pr[q*4+1], pr[q*4+2], pr[q*4+3]);

    float bv = pr[0]; int bi = 0;
    #pragma unroll
    for (int e = 1; e < 16; ++e) if (pr[e] > bv) { bv = pr[e]; bi = e; }
    float sv = -1.0f; int si = 0;
    #pragma unroll
    for (int e = 0; e < 16; ++e) if (e != bi && pr[e] > sv) { sv = pr[e]; si = e; }
    float ts = fmaxf(fabsf(bv) + fabsf(sv), 1e-12f);
    out[OFF_TP + (size_t)token * 2 + 0] = bv / ts;
    out[OFF_TP + (size_t)token * 2 + 1] = sv / ts;
    out[OFF_TI + (size_t)token * 2 + 0] = (float)bi;
    out[OFF_TI + (size_t)token * 2 + 1] = (float)si;
}

extern "C" void kernel_launch(void* const* d_in, const int* in_sizes, int n_in,
                              void* d_out, int out_size, void* d_ws, size_t ws_size,
                              hipStream_t stream) {
    const float* xg  = (const float*)d_in[0];
    const float* w1a = (const float*)d_in[1];
    const float* b1a = (const float*)d_in[2];
    const float* w2a = (const float*)d_in[3];
    const float* b2a = (const float*)d_in[4];
    const float* w1p = (const float*)d_in[5];
    const float* b1p = (const float*)d_in[6];
    const float* w2p = (const float*)d_in[7];
    const float* b2p = (const float*)d_in[8];
    const float* ent = (const float*)d_in[9];
    float* out = (float*)d_out;

    if (ws_size >= (size_t)4 * 1024 * 1024) {
        _Float16* wt = (_Float16*)d_ws;
        qir_wtrans<<<1024, 256, 0, stream>>>(w1a, w1p, wt);
        qir_gemm<<<512, 512, 147456, stream>>>(xg, wt, b1a, w2a, b2a, b1p, w2p, b2p, out);
    } else {
        qir_mlp<<<NTOK / 64, 512, 0, stream>>>(xg, w1a, b1a, w2a, b2a,
                                               w1p, b1p, w2p, b2p, out);
    }
    qir_epilogue<<<NTOK / 256, 256, 0, stream>>>(ent, out);
}

// Round 3
// 129.682 us; speedup vs baseline: 5.3446x; 1.2083x over previous
//
#include <hip/hip_runtime.h>
#include <math.h>

#define NTOK   16384
#define HDIM   1024
#define HHALF  512
#define NE     16

// d_out layout (concatenated reference outputs, all f32; indices stored as float)
#define OFF_TP  0
#define OFF_TI  (NTOK * 2)
#define OFF_DEC (NTOK * 4)
#define OFF_PH  (OFF_DEC + NTOK * NE)
#define OFF_PR  (OFF_PH + NTOK * NE)

typedef _Float16 half8 __attribute__((ext_vector_type(8)));
typedef _Float16 half4 __attribute__((ext_vector_type(4)));
typedef float f32x16 __attribute__((ext_vector_type(16)));
typedef float f32x4 __attribute__((ext_vector_type(4)));

#define LO_SCALE     2048.0f
#define LO_SCALE_INV (1.0f / 2048.0f)
#define MFMA32(a,b,c) __builtin_amdgcn_mfma_f32_32x32x16_f16(a,b,c,0,0,0)
#define MFMA16(a,b,c) __builtin_amdgcn_mfma_f32_16x16x32_f16(a,b,c,0,0,0)

__device__ __forceinline__ float gelu_exact(float x) {
    return 0.5f * x * (1.0f + erff(x * 0.70710678118654752440f));
}

__device__ __forceinline__ void cvt_split(float4 v, half4& hi, half4& lo) {
    _Float16 h0 = (_Float16)v.x, h1 = (_Float16)v.y,
             h2 = (_Float16)v.z, h3 = (_Float16)v.w;
    hi = (half4){h0, h1, h2, h3};
    lo = (half4){(_Float16)((v.x - (float)h0) * LO_SCALE),
                 (_Float16)((v.y - (float)h1) * LO_SCALE),
                 (_Float16)((v.z - (float)h2) * LO_SCALE),
                 (_Float16)((v.w - (float)h3) * LO_SCALE)};
}

// ---------------------------------------------------------------------------
// Prologue: build register-fragment B image in ws AND zero the PH/PR raw-sum
// accumulation regions of d_out (gemm blocks atomicAdd into them).
// Image (f16 elems): addr16 = 8*u where u = ((((ph*32+kc)*8+sl)*8+f)*64+l);
// f = nf*4 + kh*2 + pl. Value: col = sl*64+nf*32+(l&31),
// k = kc*32+kh*16+(l>>5)*8+j; pl=0 -> f16(W[k][col]), pl=1 -> (W-hi)*2048.
// ---------------------------------------------------------------------------
__global__ void __launch_bounds__(256)
qir_wtrans(const float* __restrict__ w1a, const float* __restrict__ w1p,
           _Float16* __restrict__ wt, float* __restrict__ out)
{
    int u = blockIdx.x * 256 + threadIdx.x;   // 0..262143
    out[OFF_PH + u] = 0.0f;
    out[OFF_PH + 262144 + u] = 0.0f;

    int l  = u & 63;
    int f  = (u >> 6) & 7;
    int sl = (u >> 9) & 7;
    int kc = (u >> 12) & 31;
    int ph = u >> 17;
    int nf = f >> 2, kh = (f >> 1) & 1, pl = f & 1;
    int col = sl * 64 + nf * 32 + (l & 31);
    int k0  = kc * 32 + kh * 16 + (l >> 5) * 8;
    const float* __restrict__ W = ph ? w1p : w1a;
    half8 v;
    #pragma unroll
    for (int j = 0; j < 8; ++j) {
        float x = W[(size_t)(k0 + j) * HHALF + col];
        _Float16 h = (_Float16)x;
        v[j] = pl ? (_Float16)((x - (float)h) * LO_SCALE) : h;
    }
    *(half8*)&wt[(size_t)u * 8] = v;
}

// ---------------------------------------------------------------------------
// Main GEMM: block = 128 tokens x 256 cols x one phase. B frags loaded
// global->reg (L2-resident, no LDS staging drain); A staged in 2x16KB LDS
// (transposed octet layout, conflict-free). Fused gelu + partial GEMM2,
// atomicAdd raw sums into d_out (zero-initialized by qir_wtrans).
// ---------------------------------------------------------------------------
__device__ __forceinline__ void kstep(
    int kc, const float* __restrict__ aptr, const _Float16* __restrict__ bptr,
    char* Acur, char* Anxt, int a_rd, int a_off0, int a_off1,
    half8 (&Bc)[8], half8 (&Bn)[8],
    float4 (&xw)[2], float4 (&xl)[2],
    f32x16& a00, f32x16& a01, f32x16& a10, f32x16& a11,
    f32x16& c00, f32x16& c01, f32x16& c10, f32x16& c11)
{
    if (kc + 2 < 32) {
        xl[0] = *(const float4*)(aptr + (kc + 2) * 32);
        xl[1] = *(const float4*)(aptr + (kc + 2) * 32 + 16);
    }
    if (kc + 1 < 32) {
        #pragma unroll
        for (int f = 0; f < 8; ++f)
            Bn[f] = *(const half8*)(bptr + (size_t)(kc + 1) * 32768 + f * 512);
    }
    #pragma unroll
    for (int kh = 0; kh < 2; ++kh) {
        const char* Ah = Acur + kh * 4096 + a_rd;
        half8 ah0 = *(const half8*)(Ah);
        half8 ah1 = *(const half8*)(Ah + 512);
        half8 al0 = *(const half8*)(Ah + 8192);
        half8 al1 = *(const half8*)(Ah + 8192 + 512);
        half8 bh0 = Bc[kh * 2],     bl0 = Bc[kh * 2 + 1];
        half8 bh1 = Bc[4 + kh * 2], bl1 = Bc[4 + kh * 2 + 1];
        a00 = MFMA32(ah0, bh0, a00); c00 = MFMA32(al0, bh0, c00); c00 = MFMA32(ah0, bl0, c00);
        a01 = MFMA32(ah0, bh1, a01); c01 = MFMA32(al0, bh1, c01); c01 = MFMA32(ah0, bl1, c01);
        a10 = MFMA32(ah1, bh0, a10); c10 = MFMA32(al1, bh0, c10); c10 = MFMA32(ah1, bl0, c10);
        a11 = MFMA32(ah1, bh1, a11); c11 = MFMA32(al1, bh1, c11); c11 = MFMA32(ah1, bl1, c11);
    }
    if (kc + 1 < 32) {
        half4 hv, lv;
        cvt_split(xw[0], hv, lv);
        *(half4*)(Anxt + a_off0) = hv; *(half4*)(Anxt + a_off0 + 8192) = lv;
        cvt_split(xw[1], hv, lv);
        *(half4*)(Anxt + a_off1) = hv; *(half4*)(Anxt + a_off1 + 8192) = lv;
    }
    __syncthreads();
}

__global__ void __launch_bounds__(512, 2)
qir_gemm(const float* __restrict__ xg, const _Float16* __restrict__ wt,
         const float* __restrict__ b1a, const float* __restrict__ w2a, const float* __restrict__ b2a,
         const float* __restrict__ b1p, const float* __restrict__ w2p, const float* __restrict__ b2p,
         float* __restrict__ out)
{
    extern __shared__ char smem[];   // 64KB: A dbuf [0,32K) (reused as H), P [32K,64K)
    const int tid = threadIdx.x;
    const int l  = tid & 63;
    const int w  = tid >> 6;
    const int wm = w >> 2;     // M half (0,1)
    const int wn = w & 3;      // n-slice within block
    const int bid  = blockIdx.x;
    const int ph   = bid & 1;
    const int nh   = (bid >> 1) & 1;
    const int mblk = bid >> 2;
    const int tok0 = mblk * 128;

    const float* __restrict__ b1 = ph ? b1p : b1a;
    const float* __restrict__ w2 = ph ? w2p : w2a;
    const float* __restrict__ b2 = ph ? b2p : b2a;
    const _Float16* __restrict__ wtp = wt + ((size_t)ph << 20);

    char* const Ab0 = smem;
    char* const Ab1 = smem + 16384;

    // A staging: thread -> (row r, k-quads kq and kq+4)
    const int r  = tid >> 2;
    const int kq = tid & 3;
    const float* __restrict__ aptr = xg + (size_t)(tok0 + r) * HDIM + kq * 4;
    const int a_off0 = (kq >> 1) * 2048 + r * 16 + (kq & 1) * 8;
    const int a_off1 = a_off0 + 4096;
    // A frag read: octet (kh*2 + (l>>5)), row wm*64 + mf*32 + (l&31)
    const int a_rd = (l >> 5) * 2048 + (wm * 64 + (l & 31)) * 16;

    // B frag pointer (f16 units)
    const _Float16* __restrict__ bptr = wtp + (nh * 4 + wn) * 4096 + (size_t)l * 8;

    f32x16 a00{}, a01{}, a10{}, a11{}, c00{}, c01{}, c10{}, c11{};
    #pragma unroll
    for (int rg = 0; rg < 16; ++rg) {
        a00[rg] = 0.f; a01[rg] = 0.f; a10[rg] = 0.f; a11[rg] = 0.f;
        c00[rg] = 0.f; c01[rg] = 0.f; c10[rg] = 0.f; c11[rg] = 0.f;
    }

    half8 Bc[8], Bn[8];
    float4 xw[2], xl[2];

    // prologue: stage kc=0 directly, preload B(0), fetch kc=1 A data
    {
        float4 v0 = *(const float4*)(aptr);
        float4 v1 = *(const float4*)(aptr + 16);
        half4 hv, lv;
        cvt_split(v0, hv, lv);
        *(half4*)(Ab0 + a_off0) = hv; *(half4*)(Ab0 + a_off0 + 8192) = lv;
        cvt_split(v1, hv, lv);
        *(half4*)(Ab0 + a_off1) = hv; *(half4*)(Ab0 + a_off1 + 8192) = lv;
    }
    #pragma unroll
    for (int f = 0; f < 8; ++f) Bc[f] = *(const half8*)(bptr + f * 512);
    xw[0] = *(const float4*)(aptr + 32);
    xw[1] = *(const float4*)(aptr + 48);
    __syncthreads();

    for (int kk = 0; kk < 16; ++kk) {
        kstep(2 * kk,     aptr, bptr, Ab0, Ab1, a_rd, a_off0, a_off1,
              Bc, Bn, xw, xl, a00, a01, a10, a11, c00, c01, c10, c11);
        kstep(2 * kk + 1, aptr, bptr, Ab1, Ab0, a_rd, a_off0, a_off1,
              Bn, Bc, xl, xw, a00, a01, a10, a11, c00, c01, c10, c11);
    }

    // combine split accumulators + bias + exact gelu (h values kept in acc)
    const int col0 = nh * 256 + wn * 64 + (l & 31);
    const float bb0 = b1[col0], bb1 = b1[col0 + 32];
    #pragma unroll
    for (int rg = 0; rg < 16; ++rg) {
        a00[rg] = gelu_exact(a00[rg] + c00[rg] * LO_SCALE_INV + bb0);
        a01[rg] = gelu_exact(a01[rg] + c01[rg] * LO_SCALE_INV + bb1);
        a10[rg] = gelu_exact(a10[rg] + c10[rg] * LO_SCALE_INV + bb0);
        a11[rg] = gelu_exact(a11[rg] + c11[rg] * LO_SCALE_INV + bb1);
    }

    // ---- fused partial GEMM2 over this block's 256 h-cols ----
    char* const Hw = smem + w * 4096;            // wave-private [4 oct][64 rows][16B]
    char* const hb = Hw + ((l >> 3) & 3) * 1024 + (l & 7) * 2;
    float* const P = (float*)(smem + 32768);     // [8 waves][64 rows][16 e]

    half8 w2h[2], w2l[2];
    #pragma unroll
    for (int nf = 0; nf < 2; ++nf) {
        #pragma unroll
        for (int j = 0; j < 8; ++j) {
            int kg = nh * 256 + wn * 64 + nf * 32 + (l >> 4) * 8 + j;
            float v = w2[(size_t)kg * NE + (l & 15)];
            _Float16 hh = (_Float16)v;
            w2h[nf][j] = hh;
            w2l[nf][j] = (_Float16)((v - (float)hh) * LO_SCALE);
        }
    }

    f32x4 acc2[4], acc2s[4];
    #pragma unroll
    for (int m16 = 0; m16 < 4; ++m16)
        #pragma unroll
        for (int rg = 0; rg < 4; ++rg) { acc2[m16][rg] = 0.f; acc2s[m16][rg] = 0.f; }

#define H2PASS(ACC0, ACC1, NF, PL)                                             \
    {                                                                          \
        _Pragma("unroll")                                                      \
        for (int rg = 0; rg < 16; ++rg) {                                      \
            int row0 = (rg & 3) + 8 * (rg >> 2) + 4 * (l >> 5);                \
            { float vv = ACC0[rg]; _Float16 hh = (_Float16)vv;                 \
              *(_Float16*)(hb + row0 * 16) =                                   \
                  (PL) ? (_Float16)(vv - (float)hh) : hh; }                    \
            { float vv = ACC1[rg]; _Float16 hh = (_Float16)vv;                 \
              *(_Float16*)(hb + (32 + row0) * 16) =                            \
                  (PL) ? (_Float16)(vv - (float)hh) : hh; }                    \
        }                                                                      \
        _Pragma("unroll")                                                      \
        for (int m16 = 0; m16 < 4; ++m16) {                                    \
            half8 a2 = *(const half8*)(Hw + (l >> 4) * 1024 +                  \
                                       (m16 * 16 + (l & 15)) * 16);            \
            acc2[m16] = MFMA16(a2, w2h[NF], acc2[m16]);                        \
            if (!(PL)) acc2s[m16] = MFMA16(a2, w2l[NF], acc2s[m16]);           \
        }                                                                      \
    }

    H2PASS(a00, a10, 0, 0)
    H2PASS(a01, a11, 1, 0)
    H2PASS(a00, a10, 0, 1)
    H2PASS(a01, a11, 1, 1)
#undef H2PASS

    #pragma unroll
    for (int m16 = 0; m16 < 4; ++m16)
        #pragma unroll
        for (int rg = 0; rg < 4; ++rg) {
            int row = m16 * 16 + ((l >> 4) << 2) + rg;
            P[w * 1024 + row * 16 + (l & 15)] =
                acc2[m16][rg] + acc2s[m16][rg] * LO_SCALE_INV;
        }
    __syncthreads();

    #pragma unroll
    for (int rep = 0; rep < 4; ++rep) {
        int oi = tid + rep * 512;
        int t = oi >> 4, e = oi & 15;
        int bw = (t >> 6) * 4, tl = t & 63;
        float sum = 0.5f * b2[e]
                  + P[(bw + 0) * 1024 + tl * 16 + e]
                  + P[(bw + 1) * 1024 + tl * 16 + e]
                  + P[(bw + 2) * 1024 + tl * 16 + e]
                  + P[(bw + 3) * 1024 + tl * 16 + e];
        atomicAdd(out + (ph ? OFF_PH : OFF_PR) + (size_t)(tok0 + t) * NE + e, sum);
    }
}

// ---------------------------------------------------------------------------
// Fallback (R1 kernel, raw-phase variant) if ws too small for the WT image.
// ---------------------------------------------------------------------------
__global__ void __launch_bounds__(512)
qir_mlp(const float* __restrict__ xg,
        const float* __restrict__ w1a, const float* __restrict__ b1a,
        const float* __restrict__ w2a, const float* __restrict__ b2a,
        const float* __restrict__ w1p, const float* __restrict__ b1p,
        const float* __restrict__ w2p, const float* __restrict__ b2p,
        float* __restrict__ out)
{
    __shared__ float sh_w[16][HHALF];
    __shared__ float sh_x[16][68];

    const int tid  = threadIdx.x;
    const int cg   = tid & 63;
    const int tg   = tid >> 6;
    const int tok0 = blockIdx.x * 64;
    const int cA   = cg * 4;
    const int cB   = 256 + cg * 4;

    for (int phase = 0; phase < 2; ++phase) {
        const float* __restrict__ w1 = phase ? w1p : w1a;
        const float* __restrict__ b1 = phase ? b1p : b1a;
        const float* __restrict__ w2 = phase ? w2p : w2a;
        const float* __restrict__ b2 = phase ? b2p : b2a;

        float acc[8][8];
        #pragma unroll
        for (int t = 0; t < 8; ++t)
            #pragma unroll
            for (int c = 0; c < 8; ++c) acc[t][c] = 0.0f;

        float4 wreg[4];
        float4 xreg = make_float4(0.f, 0.f, 0.f, 0.f);

        auto load_chunk = [&](int kc) {
            #pragma unroll
            for (int p = 0; p < 4; ++p) {
                int f  = tid + p * 512;
                int k  = f >> 7;
                int c4 = (f & 127) << 2;
                wreg[p] = *(const float4*)&w1[(kc * 16 + k) * HHALF + c4];
            }
            if (tid < 256) {
                int t  = tid >> 2;
                int k4 = (tid & 3) << 2;
                xreg = *(const float4*)&xg[(size_t)(tok0 + t) * HDIM + kc * 16 + k4];
            }
        };

        load_chunk(0);
        for (int kc = 0; kc < HDIM / 16; ++kc) {
            __syncthreads();
            #pragma unroll
            for (int p = 0; p < 4; ++p) {
                int f  = tid + p * 512;
                int k  = f >> 7;
                int c4 = (f & 127) << 2;
                *(float4*)&sh_w[k][c4] = wreg[p];
            }
            if (tid < 256) {
                int t  = tid >> 2;
                int k4 = (tid & 3) << 2;
                sh_x[k4 + 0][t] = xreg.x;
                sh_x[k4 + 1][t] = xreg.y;
                sh_x[k4 + 2][t] = xreg.z;
                sh_x[k4 + 3][t] = xreg.w;
            }
            __syncthreads();
            if (kc + 1 < HDIM / 16) load_chunk(kc + 1);

            #pragma unroll 4
            for (int k = 0; k < 16; ++k) {
                float4 xa = *(const float4*)&sh_x[k][tg * 8];
                float4 xb = *(const float4*)&sh_x[k][tg * 8 + 4];
                float4 wa = *(const float4*)&sh_w[k][cA];
                float4 wb = *(const float4*)&sh_w[k][cB];
                float xs[8] = {xa.x, xa.y, xa.z, xa.w, xb.x, xb.y, xb.z, xb.w};
                float ws[8] = {wa.x, wa.y, wa.z, wa.w, wb.x, wb.y, wb.z, wb.w};
                #pragma unroll
                for (int t = 0; t < 8; ++t)
                    #pragma unroll
                    for (int c = 0; c < 8; ++c)
                        acc[t][c] = fmaf(xs[t], ws[c], acc[t][c]);
            }
        }

        {
            float4 bA4 = *(const float4*)&b1[cA];
            float4 bB4 = *(const float4*)&b1[cB];
            float bs[8] = {bA4.x, bA4.y, bA4.z, bA4.w, bB4.x, bB4.y, bB4.z, bB4.w};
            #pragma unroll
            for (int t = 0; t < 8; ++t)
                #pragma unroll
                for (int c = 0; c < 8; ++c)
                    acc[t][c] = gelu_exact(acc[t][c] + bs[c]);
        }

        for (int e = 0; e < NE; ++e) {
            float w2v[8];
            #pragma unroll
            for (int j = 0; j < 4; ++j) {
                w2v[j]     = w2[(cA + j) * NE + e];
                w2v[4 + j] = w2[(cB + j) * NE + e];
            }
            float bias2 = b2[e];
            #pragma unroll
            for (int t = 0; t < 8; ++t) {
                float s = 0.0f;
                #pragma unroll
                for (int j = 0; j < 8; ++j) s = fmaf(acc[t][j], w2v[j], s);
                #pragma unroll
                for (int off = 1; off < 64; off <<= 1)
                    s += __shfl_xor(s, off, 64);
                if (cg == 0) {
                    float raw   = s + bias2;
                    int   token = tok0 + tg * 8 + t;
                    // raw sums in both cases; epilogue applies tanh to PH
                    out[(phase ? OFF_PH : OFF_PR) + (size_t)token * NE + e] = raw;
                }
            }
        }
    }
}

// ---------------------------------------------------------------------------
// Per-token epilogue: tanh on raw phases; softmax/rotations/probs/top-2.
// ---------------------------------------------------------------------------
__global__ void __launch_bounds__(256)
qir_epilogue(const float* __restrict__ ent, float* __restrict__ out)
{
    __shared__ float sh_c[120], sh_s[120];
    const int tid = threadIdx.x;
    if (tid < 120) {
        int rem = tid, i = 0;
        while (rem >= 15 - i) { rem -= 15 - i; ++i; }
        int j = i + 1 + rem;
        float ang = ent[i * NE + j] * 0.5f;
        sh_c[tid] = cosf(ang);
        sh_s[tid] = sinf(ang);
    }
    __syncthreads();

    const int token = blockIdx.x * 256 + tid;

    // raw phases -> tanh * pi
    #pragma unroll
    for (int q = 0; q < 4; ++q) {
        float4 v = *(const float4*)&out[OFF_PH + (size_t)token * NE + q * 4];
        v.x = tanhf(v.x) * 3.14159265358979323846f;
        v.y = tanhf(v.y) * 3.14159265358979323846f;
        v.z = tanhf(v.z) * 3.14159265358979323846f;
        v.w = tanhf(v.w) * 3.14159265358979323846f;
        *(float4*)&out[OFF_PH + (size_t)token * NE + q * 4] = v;
    }

    float a[16];
    #pragma unroll
    for (int q = 0; q < 4; ++q) {
        float4 v = *(const float4*)&out[OFF_PR + (size_t)token * NE + q * 4];
        a[q*4+0] = v.x; a[q*4+1] = v.y; a[q*4+2] = v.z; a[q*4+3] = v.w;
    }

    float m = fabsf(a[0]);
    #pragma unroll
    for (int e = 1; e < 16; ++e) m = fmaxf(m, fabsf(a[e]));
    float ssum = 0.0f;
    #pragma unroll
    for (int e = 0; e < 16; ++e) { a[e] = expf(fabsf(a[e]) - m); ssum += a[e]; }
    float inv = 1.0f / ssum;
    #pragma unroll
    for (int e = 0; e < 16; ++e) a[e] = sqrtf(a[e] * inv);

    {
        int p = 0;
        #pragma unroll
        for (int i = 0; i < 16; ++i) {
            #pragma unroll
            for (int j = i + 1; j < 16; ++j) {
                float c = sh_c[p], s = sh_s[p]; ++p;
                float ai = a[i], aj = a[j];
                a[i] = c * ai - s * aj;
                a[j] = s * ai + c * aj;
            }
        }
    }

    #pragma unroll
    for (int q = 0; q < 4; ++q)
        *(float4*)&out[OFF_DEC + (size_t)token * NE + q * 4] =
            make_float4(a[q*4], a[q*4+1], a[q*4+2], a[q*4+3]);

    float pr[16];
    float s2 = 0.0f;
    #pragma unroll
    for (int e = 0; e < 16; ++e) { pr[e] = a[e] * a[e]; s2 += pr[e]; }
    float inv2 = 1.0f / fmaxf(s2, 1e-12f);
    #pragma unroll
    for (int e = 0; e < 16; ++e) pr[e] *= inv2;
    #pragma unroll
    for (int q = 0; q < 4; ++q)
        *(float4*)&out[OFF_PR + (size_t)token * NE + q * 4] =
            make_float4(pr[q*4], pr[q*4+1], pr[q*4+2], pr[q*4+3]);

    float bv = pr[0]; int bi = 0;
    #pragma unroll
    for (int e = 1; e < 16; ++e) if (pr[e] > bv) { bv = pr[e]; bi = e; }
    float sv = -1.0f; int si = 0;
    #pragma unroll
    for (int e = 0; e < 16; ++e) if (e != bi && pr[e] > sv) { sv = pr[e]; si = e; }
    float ts = fmaxf(fabsf(bv) + fabsf(sv), 1e-12f);
    out[OFF_TP + (size_t)token * 2 + 0] = bv / ts;
    out[OFF_TP + (size_t)token * 2 + 1] = sv / ts;
    out[OFF_TI + (size_t)token * 2 + 0] = (float)bi;
    out[OFF_TI + (size_t)token * 2 + 1] = (float)si;
}

extern "C" void kernel_launch(void* const* d_in, const int* in_sizes, int n_in,
                              void* d_out, int out_size, void* d_ws, size_t ws_size,
                              hipStream_t stream) {
    const float* xg  = (const float*)d_in[0];
    const float* w1a = (const float*)d_in[1];
    const float* b1a = (const float*)d_in[2];
    const float* w2a = (const float*)d_in[3];
    const float* b2a = (const float*)d_in[4];
    const float* w1p = (const float*)d_in[5];
    const float* b1p = (const float*)d_in[6];
    const float* w2p = (const float*)d_in[7];
    const float* b2p = (const float*)d_in[8];
    const float* ent = (const float*)d_in[9];
    float* out = (float*)d_out;

    if (ws_size >= (size_t)4 * 1024 * 1024) {
        _Float16* wt = (_Float16*)d_ws;
        qir_wtrans<<<1024, 256, 0, stream>>>(w1a, w1p, wt, out);
        qir_gemm<<<512, 512, 65536, stream>>>(xg, wt, b1a, w2a, b2a,
                                              b1p, w2p, b2p, out);
    } else {
        qir_mlp<<<NTOK / 64, 512, 0, stream>>>(xg, w1a, b1a, w2a, b2a,
                                               w1p, b1p, w2p, b2p, out);
    }
    qir_epilogue<<<NTOK / 256, 256, 0, stream>>>(ent, out);
}